// Round 1
// baseline (24998.953 us; speedup 1.0000x reference)
//
#include <hip/hip_runtime.h>
#include <math.h>

namespace {
constexpr int kB = 2;
constexpr int kT = 2048;
constexpr int kD = 1024;
constexpr int kH = 16;
constexpr int kL = 8;
constexpr int kInner = 4096;
constexpr int kM = kB * kT;  // 4096 token rows
constexpr float kEps = 1e-5f;
}

__device__ __forceinline__ float wave_max64(float v) {
#pragma unroll
  for (int off = 32; off > 0; off >>= 1) v = fmaxf(v, __shfl_xor(v, off));
  return v;
}
__device__ __forceinline__ float wave_sum64(float v) {
#pragma unroll
  for (int off = 32; off > 0; off >>= 1) v += __shfl_xor(v, off);
  return v;
}

// ---------------- LayerNorm: one 256-thread block per row of 1024 ----------------
__global__ __launch_bounds__(256) void ln_kernel(
    const float* __restrict__ in, const float* __restrict__ w,
    const float* __restrict__ b, float* __restrict__ out) {
  const int row = blockIdx.x;
  const int tid = threadIdx.x;
  const float4 v = ((const float4*)(in + (size_t)row * kD))[tid];
  float sum = v.x + v.y + v.z + v.w;
  float sq = v.x * v.x + v.y * v.y + v.z * v.z + v.w * v.w;
#pragma unroll
  for (int off = 32; off > 0; off >>= 1) {
    sum += __shfl_down(sum, off);
    sq += __shfl_down(sq, off);
  }
  __shared__ float s1[4], s2[4];
  const int wave = tid >> 6, lane = tid & 63;
  if (lane == 0) { s1[wave] = sum; s2[wave] = sq; }
  __syncthreads();
  const float ts = s1[0] + s1[1] + s1[2] + s1[3];
  const float tq = s2[0] + s2[1] + s2[2] + s2[3];
  const float mean = ts * (1.0f / kD);
  const float var = tq * (1.0f / kD) - mean * mean;
  const float rs = rsqrtf(var + kEps);
  const float4 w4 = ((const float4*)w)[tid];
  const float4 b4 = ((const float4*)b)[tid];
  float4 o;
  o.x = (v.x - mean) * rs * w4.x + b4.x;
  o.y = (v.y - mean) * rs * w4.y + b4.y;
  o.z = (v.z - mean) * rs * w4.z + b4.z;
  o.w = (v.w - mean) * rs * w4.w + b4.w;
  ((float4*)(out + (size_t)row * kD))[tid] = o;
}

// ---------------- fp32 GEMM: C[M,N] = A[M,K]·W[K,N] + bias (+res) (+relu) -------
// 64x64 tile, K-step 16, 256 threads, 4x4 microtile.
template <bool RELU, bool RES>
__global__ __launch_bounds__(256) void gemm_kernel(
    const float* __restrict__ A, const float* __restrict__ W,
    const float* __restrict__ bias, const float* __restrict__ res,
    float* __restrict__ C, int N, int K) {
  __shared__ float As[16][68];
  __shared__ float Bs[16][68];
  const int tid = threadIdx.x;
  const int tx = tid & 15, ty = tid >> 4;
  const int n0 = blockIdx.x * 64, m0 = blockIdx.y * 64;

  float acc[4][4];
#pragma unroll
  for (int i = 0; i < 4; ++i)
#pragma unroll
    for (int j = 0; j < 4; ++j) acc[i][j] = 0.f;

  const int ar = tid >> 2;            // 0..63 (m within tile)
  const int ak = (tid & 3) << 2;      // 0..12 (k within tile)
  const int br = tid >> 4;            // 0..15 (k within tile)
  const int bn = (tid & 15) << 2;     // 0..60 (n within tile)
  const float* Aptr = A + (size_t)(m0 + ar) * K + ak;
  const float* Wptr = W + (size_t)br * N + n0 + bn;

  for (int k0 = 0; k0 < K; k0 += 16) {
    const float4 av = *(const float4*)(Aptr + k0);
    const float4 bv = *(const float4*)(Wptr + (size_t)k0 * N);
    As[ak + 0][ar] = av.x;
    As[ak + 1][ar] = av.y;
    As[ak + 2][ar] = av.z;
    As[ak + 3][ar] = av.w;
    *(float4*)&Bs[br][bn] = bv;
    __syncthreads();
#pragma unroll
    for (int kk = 0; kk < 16; ++kk) {
      const float4 a4 = *(const float4*)&As[kk][ty << 2];
      const float4 b4 = *(const float4*)&Bs[kk][tx << 2];
      const float aa[4] = {a4.x, a4.y, a4.z, a4.w};
      const float bb[4] = {b4.x, b4.y, b4.z, b4.w};
#pragma unroll
      for (int i = 0; i < 4; ++i)
#pragma unroll
        for (int j = 0; j < 4; ++j) acc[i][j] += aa[i] * bb[j];
    }
    __syncthreads();
  }

  const float4 bias4 = *(const float4*)(bias + n0 + (tx << 2));
#pragma unroll
  for (int i = 0; i < 4; ++i) {
    const int m = m0 + (ty << 2) + i;
    float4 o;
    o.x = acc[i][0] + bias4.x;
    o.y = acc[i][1] + bias4.y;
    o.z = acc[i][2] + bias4.z;
    o.w = acc[i][3] + bias4.w;
    if (RES) {
      const float4 r4 = *(const float4*)(res + (size_t)m * N + n0 + (tx << 2));
      o.x += r4.x; o.y += r4.y; o.z += r4.z; o.w += r4.w;
    }
    if (RELU) {
      o.x = fmaxf(o.x, 0.f); o.y = fmaxf(o.y, 0.f);
      o.z = fmaxf(o.z, 0.f); o.w = fmaxf(o.w, 0.f);
    }
    *(float4*)(C + (size_t)m * N + n0 + (tx << 2)) = o;
  }
}

// ---------------- causal flash attention (fp32, online softmax) -----------------
// Block = 16 consecutive q-rows of one (b,h). 4 waves x 4 rows/wave.
// K-tile: 64 keys staged [key][d] (pad 68); V-tile staged transposed [d][key].
__global__ __launch_bounds__(256) void attn_kernel(
    const float* __restrict__ qkv, const float* __restrict__ amaskp,
    float* __restrict__ ctx) {
  __shared__ float kt[64][68];    // [key][dim]
  __shared__ float vtT[64][68];   // [dim][key]
  __shared__ float qs[16][68];    // [row][dim], pre-scaled
  __shared__ float ps[16][68];    // [row][key]
  __shared__ float am[64];

  const int tid = threadIdx.x;
  const int wave = tid >> 6, lane = tid & 63;
  const int bh = blockIdx.y;
  const int bb = bh >> 4;         // batch
  const int hh = bh & 15;         // head
  const int q_base = blockIdx.x * 16;
  const int r0 = wave * 4;

  const float* base = qkv + (size_t)bb * kT * 3072;
  const float* kbase = base + 1024 + hh * 64;
  const float* vbase = base + 2048 + hh * 64;

  // load Q tile (16 rows x 64 dims), pre-scaled by 1/sqrt(64)
  {
    const int r = tid >> 4;
    const int d0 = (tid & 15) << 2;
    float4 qv = *(const float4*)(base + (size_t)(q_base + r) * 3072 + hh * 64 + d0);
    qv.x *= 0.125f; qv.y *= 0.125f; qv.z *= 0.125f; qv.w *= 0.125f;
    *(float4*)&qs[r][d0] = qv;
  }

  float m[4], l[4], acc[4];
#pragma unroll
  for (int r = 0; r < 4; ++r) { m[r] = -1e30f; l[r] = 0.f; acc[r] = 0.f; }

  const int q_max = q_base + 15;
  for (int k0 = 0; k0 <= q_max; k0 += 64) {
    // stage K and V^T tiles
#pragma unroll
    for (int i = 0; i < 4; ++i) {
      const int qd = (i << 8) + tid;   // 0..1023 quad index
      const int r = qd >> 4;           // key 0..63
      const int d0 = (qd & 15) << 2;   // dim 0..60
      const int k = k0 + r;
      float4 kv = {0.f, 0.f, 0.f, 0.f}, vv = {0.f, 0.f, 0.f, 0.f};
      if (k < kT) {
        kv = *(const float4*)(kbase + (size_t)k * 3072 + d0);
        vv = *(const float4*)(vbase + (size_t)k * 3072 + d0);
      }
      *(float4*)&kt[r][d0] = kv;
      vtT[d0 + 0][r] = vv.x;
      vtT[d0 + 1][r] = vv.y;
      vtT[d0 + 2][r] = vv.z;
      vtT[d0 + 3][r] = vv.w;
    }
    if (tid < 64) {
      const int k = k0 + tid;
      am[tid] = (k < kT) ? (1.0f - amaskp[bb * kT + k]) * (-10000.0f) : 0.f;
    }
    __syncthreads();

    // S = Q·K^T : lane = key, 4 q-rows per wave reuse the kt read
    float s[4] = {0.f, 0.f, 0.f, 0.f};
#pragma unroll
    for (int d0 = 0; d0 < 64; d0 += 4) {
      const float4 kv = *(const float4*)&kt[lane][d0];
#pragma unroll
      for (int r = 0; r < 4; ++r) {
        const float4 qv = *(const float4*)&qs[r0 + r][d0];
        s[r] += qv.x * kv.x + qv.y * kv.y + qv.z * kv.z + qv.w * kv.w;
      }
    }

    // online softmax per row
    const int kj = k0 + lane;
#pragma unroll
    for (int r = 0; r < 4; ++r) {
      const int qrow = q_base + r0 + r;
      const float sr = (kj <= qrow) ? (s[r] + am[lane]) : -1e30f;
      const float mt = wave_max64(sr);
      const float mn = fmaxf(m[r], mt);
      const float alpha = __expf(m[r] - mn);
      const float p = __expf(sr - mn);
      l[r] = l[r] * alpha + wave_sum64(p);
      m[r] = mn;
      acc[r] *= alpha;
      ps[r0 + r][lane] = p;   // same-wave write->read: HW-ordered
    }

    // O += P·V : lane = dim, reuse vtT read across 4 rows
#pragma unroll
    for (int j0 = 0; j0 < 64; j0 += 4) {
      const float4 vv = *(const float4*)&vtT[lane][j0];
#pragma unroll
      for (int r = 0; r < 4; ++r) {
        const float4 pv = *(const float4*)&ps[r0 + r][j0];
        acc[r] += pv.x * vv.x + pv.y * vv.y + pv.z * vv.z + pv.w * vv.w;
      }
    }
    __syncthreads();
  }

#pragma unroll
  for (int r = 0; r < 4; ++r) {
    ctx[((size_t)(bb * kT + q_base + r0 + r)) * 1024 + hh * 64 + lane] =
        acc[r] / l[r];
  }
}

// --------------------------------- launcher -------------------------------------
extern "C" void kernel_launch(void* const* d_in, const int* in_sizes, int n_in,
                              void* d_out, int out_size, void* d_ws, size_t ws_size,
                              hipStream_t stream) {
  const float* emb   = (const float*)d_in[0];
  const float* amask = (const float*)d_in[1];
  const float* ln1w  = (const float*)d_in[2];
  const float* ln1b  = (const float*)d_in[3];
  const float* attnw = (const float*)d_in[4];
  const float* attnb = (const float*)d_in[5];
  const float* projw = (const float*)d_in[6];
  const float* projb = (const float*)d_in[7];
  const float* ln2w  = (const float*)d_in[8];
  const float* ln2b  = (const float*)d_in[9];
  const float* fcw   = (const float*)d_in[10];
  const float* fcb   = (const float*)d_in[11];
  const float* fcpw  = (const float*)d_in[12];
  const float* fcpb  = (const float*)d_in[13];
  const float* lnfw  = (const float*)d_in[14];
  const float* lnfb  = (const float*)d_in[15];
  float* out = (float*)d_out;

  float* h   = (float*)d_ws;                       // [4096,1024]
  float* x   = h + (size_t)kM * kD;                // [4096,1024]
  float* ctx = x + (size_t)kM * kD;                // [4096,1024]
  float* big = ctx + (size_t)kM * kD;              // qkv [4096,3072] / ffn [4096,4096]

  hipMemcpyAsync(h, emb, sizeof(float) * (size_t)kM * kD,
                 hipMemcpyDeviceToDevice, stream);

  const dim3 blk(256);
  for (int l = 0; l < kL; ++l) {
    ln_kernel<<<kM, blk, 0, stream>>>(h, ln1w + l * kD, ln1b + l * kD, x);
    gemm_kernel<false, false><<<dim3(3072 / 64, kM / 64), blk, 0, stream>>>(
        x, attnw + (size_t)l * kD * 3072, attnb + l * 3072, nullptr, big, 3072, kD);
    attn_kernel<<<dim3(kT / 16, kB * kH), blk, 0, stream>>>(big, amask, ctx);
    gemm_kernel<false, true><<<dim3(1024 / 64, kM / 64), blk, 0, stream>>>(
        ctx, projw + (size_t)l * kD * kD, projb + l * kD, h, h, 1024, kD);
    ln_kernel<<<kM, blk, 0, stream>>>(h, ln2w + l * kD, ln2b + l * kD, x);
    gemm_kernel<true, false><<<dim3(4096 / 64, kM / 64), blk, 0, stream>>>(
        x, fcw + (size_t)l * kD * kInner, fcb + l * kInner, nullptr, big, kInner, kD);
    gemm_kernel<false, true><<<dim3(1024 / 64, kM / 64), blk, 0, stream>>>(
        big, fcpw + (size_t)l * kInner * kD, fcpb + l * kD, h, h, 1024, kInner);
  }
  ln_kernel<<<kM, blk, 0, stream>>>(h, lnfw, lnfb, out);
}

// Round 2
// 13036.937 us; speedup vs baseline: 1.9175x; 1.9175x over previous
//
#include <hip/hip_runtime.h>
#include <math.h>

namespace {
constexpr int kB = 2;
constexpr int kT = 2048;
constexpr int kD = 1024;
constexpr int kH = 16;
constexpr int kL = 8;
constexpr int kInner = 4096;
constexpr int kM = kB * kT;  // 4096 token rows
constexpr float kEps = 1e-5f;
}

typedef __attribute__((ext_vector_type(8))) short bf16x8;
typedef __attribute__((ext_vector_type(4))) float f32x4;

__device__ __forceinline__ short f2bf(float f) {
  union { float f; unsigned u; } v{f};
  unsigned r = (v.u + 0x7FFF + ((v.u >> 16) & 1)) >> 16;
  return (short)r;
}

// ---------------- LayerNorm: one 256-thread block per row of 1024 ----------------
__global__ __launch_bounds__(256) void ln_kernel(
    const float* __restrict__ in, const float* __restrict__ w,
    const float* __restrict__ b, float* __restrict__ out) {
  const int row = blockIdx.x;
  const int tid = threadIdx.x;
  const float4 v = ((const float4*)(in + (size_t)row * kD))[tid];
  float sum = v.x + v.y + v.z + v.w;
  float sq = v.x * v.x + v.y * v.y + v.z * v.z + v.w * v.w;
#pragma unroll
  for (int off = 32; off > 0; off >>= 1) {
    sum += __shfl_down(sum, off);
    sq += __shfl_down(sq, off);
  }
  __shared__ float s1[4], s2[4];
  const int wave = tid >> 6, lane = tid & 63;
  if (lane == 0) { s1[wave] = sum; s2[wave] = sq; }
  __syncthreads();
  const float ts = s1[0] + s1[1] + s1[2] + s1[3];
  const float tq = s2[0] + s2[1] + s2[2] + s2[3];
  const float mean = ts * (1.0f / kD);
  const float var = tq * (1.0f / kD) - mean * mean;
  const float rs = rsqrtf(var + kEps);
  const float4 w4 = ((const float4*)w)[tid];
  const float4 b4 = ((const float4*)b)[tid];
  float4 o;
  o.x = (v.x - mean) * rs * w4.x + b4.x;
  o.y = (v.y - mean) * rs * w4.y + b4.y;
  o.z = (v.z - mean) * rs * w4.z + b4.z;
  o.w = (v.w - mean) * rs * w4.w + b4.w;
  ((float4*)(out + (size_t)row * kD))[tid] = o;
}

// ---------------- fp32 GEMM: C[M,N] = A[M,K]·W[K,N] + bias (+res) (+relu) -------
template <bool RELU, bool RES>
__global__ __launch_bounds__(256) void gemm_kernel(
    const float* __restrict__ A, const float* __restrict__ W,
    const float* __restrict__ bias, const float* __restrict__ res,
    float* __restrict__ C, int N, int K) {
  __shared__ float As[16][68];
  __shared__ float Bs[16][68];
  const int tid = threadIdx.x;
  const int tx = tid & 15, ty = tid >> 4;
  const int n0 = blockIdx.x * 64, m0 = blockIdx.y * 64;

  float acc[4][4];
#pragma unroll
  for (int i = 0; i < 4; ++i)
#pragma unroll
    for (int j = 0; j < 4; ++j) acc[i][j] = 0.f;

  const int ar = tid >> 2;
  const int ak = (tid & 3) << 2;
  const int br = tid >> 4;
  const int bn = (tid & 15) << 2;
  const float* Aptr = A + (size_t)(m0 + ar) * K + ak;
  const float* Wptr = W + (size_t)br * N + n0 + bn;

  for (int k0 = 0; k0 < K; k0 += 16) {
    const float4 av = *(const float4*)(Aptr + k0);
    const float4 bv = *(const float4*)(Wptr + (size_t)k0 * N);
    As[ak + 0][ar] = av.x;
    As[ak + 1][ar] = av.y;
    As[ak + 2][ar] = av.z;
    As[ak + 3][ar] = av.w;
    *(float4*)&Bs[br][bn] = bv;
    __syncthreads();
#pragma unroll
    for (int kk = 0; kk < 16; ++kk) {
      const float4 a4 = *(const float4*)&As[kk][ty << 2];
      const float4 b4 = *(const float4*)&Bs[kk][tx << 2];
      const float aa[4] = {a4.x, a4.y, a4.z, a4.w};
      const float bb[4] = {b4.x, b4.y, b4.z, b4.w};
#pragma unroll
      for (int i = 0; i < 4; ++i)
#pragma unroll
        for (int j = 0; j < 4; ++j) acc[i][j] += aa[i] * bb[j];
    }
    __syncthreads();
  }

  const float4 bias4 = *(const float4*)(bias + n0 + (tx << 2));
#pragma unroll
  for (int i = 0; i < 4; ++i) {
    const int m = m0 + (ty << 2) + i;
    float4 o;
    o.x = acc[i][0] + bias4.x;
    o.y = acc[i][1] + bias4.y;
    o.z = acc[i][2] + bias4.z;
    o.w = acc[i][3] + bias4.w;
    if (RES) {
      const float4 r4 = *(const float4*)(res + (size_t)m * N + n0 + (tx << 2));
      o.x += r4.x; o.y += r4.y; o.z += r4.z; o.w += r4.w;
    }
    if (RELU) {
      o.x = fmaxf(o.x, 0.f); o.y = fmaxf(o.y, 0.f);
      o.z = fmaxf(o.z, 0.f); o.w = fmaxf(o.w, 0.f);
    }
    *(float4*)(C + (size_t)m * N + n0 + (tx << 2)) = o;
  }
}

// ---------------- MFMA bf16 flash attention ------------------------------------
// Block: one (b,h), 64 q rows. 4 waves x 16-q-row MFMA tile. K-tile = 64 keys.
// K/V staged fp32->bf16 in LDS in fragment order: frag f = [64 lanes][8 elems],
// so every B-frag read is one conflict-free lane-contiguous ds_read_b128.
//   K frag (t,c): lane L holds K[16t+(L&15)][32c+8*(L>>4)+j]   (S = Q*K^T)
//   V frag (u,c): lane L holds V[32c+8*(L>>4)+j][16u+(L&15)]   (O = P*V)
// C/D layout (m89-verified): col=lane&15, row=(lane>>4)*4+reg.
// P: C-layout -> A-layout via wave-private LDS round trip (no barrier needed).
__global__ __launch_bounds__(256) void attn_kernel(
    const float* __restrict__ qkv, const float* __restrict__ amaskp,
    float* __restrict__ ctx) {
  __shared__ short kf[8 * 512];        // 8 KB
  __shared__ short vf[8 * 512];        // 8 KB
  __shared__ float ptl[4][16][65];     // 16.25 KB, wave-private slabs
  __shared__ float am_s[64];

  const int tid = threadIdx.x;
  const int w = tid >> 6;
  const int lane = tid & 63;
  const int n = lane & 15;
  const int quad = lane >> 4;
  const int bh = blockIdx.y;
  const int bb = bh >> 4;
  const int hh = bh & 15;
  const int qb = gridDim.x - 1 - blockIdx.x;  // heavy causal blocks first
  const int q0 = qb * 64;

  const float* base = qkv + (size_t)bb * kT * 3072;
  const float* kbase = base + 1024 + hh * 64;
  const float* vbase = base + 2048 + hh * 64;

  // ---- Q A-fragments in registers, pre-scaled by 1/8 ----
  bf16x8 qa[2];
  {
    const int row = q0 + w * 16 + n;
    const float* qrow = base + (size_t)row * 3072 + hh * 64 + quad * 8;
#pragma unroll
    for (int c = 0; c < 2; ++c) {
      const float4 a = *(const float4*)(qrow + c * 32);
      const float4 b = *(const float4*)(qrow + c * 32 + 4);
      qa[c][0] = f2bf(a.x * 0.125f); qa[c][1] = f2bf(a.y * 0.125f);
      qa[c][2] = f2bf(a.z * 0.125f); qa[c][3] = f2bf(a.w * 0.125f);
      qa[c][4] = f2bf(b.x * 0.125f); qa[c][5] = f2bf(b.y * 0.125f);
      qa[c][6] = f2bf(b.z * 0.125f); qa[c][7] = f2bf(b.w * 0.125f);
    }
  }

  f32x4 O[4];
#pragma unroll
  for (int u = 0; u < 4; ++u) O[u] = (f32x4)0.f;
  float m_r[4], l_r[4];
#pragma unroll
  for (int r = 0; r < 4; ++r) { m_r[r] = -1e30f; l_r[r] = 0.f; }

  const int skey = tid >> 4;          // staging: key-within-pass
  const int sd0 = (tid & 15) << 2;    // staging: dim
  for (int k0 = 0; k0 <= q0; k0 += 64) {
    // ---- stage K,V tiles (fp32 -> bf16, fragment-ordered) ----
#pragma unroll
    for (int p = 0; p < 4; ++p) {
      const int key = p * 16 + skey;
      const float4 kv = *(const float4*)(kbase + (size_t)(k0 + key) * 3072 + sd0);
      const float4 vv = *(const float4*)(vbase + (size_t)(k0 + key) * 3072 + sd0);
      // K: frag (t=key>>4, c=sd0>>5), lane' = ((sd0&31)>>3)*16 + (key&15), j0=sd0&7
      short* kw = kf + ((key >> 4) * 2 + (sd0 >> 5)) * 512 +
                  ((((sd0 & 31) >> 3) << 4) + (key & 15)) * 8 + (sd0 & 7);
      kw[0] = f2bf(kv.x); kw[1] = f2bf(kv.y); kw[2] = f2bf(kv.z); kw[3] = f2bf(kv.w);
      // V: frag (u=d>>4, c=key>>5), lane' = (((key&31)>>3)<<4) + (d&15), j=key&7
      const float vvv[4] = {vv.x, vv.y, vv.z, vv.w};
#pragma unroll
      for (int i = 0; i < 4; ++i) {
        const int d = sd0 + i;
        vf[((d >> 4) * 2 + (key >> 5)) * 512 +
           ((((key & 31) >> 3) << 4) + (d & 15)) * 8 + (key & 7)] = f2bf(vvv[i]);
      }
    }
    if (tid < 64)
      am_s[tid] = (1.0f - amaskp[bb * kT + k0 + tid]) * (-10000.0f);
    __syncthreads();

    // ---- S = Q*K^T : 4 key-subtiles x 2 K-chunks ----
    f32x4 sf[4];
#pragma unroll
    for (int t = 0; t < 4; ++t) {
      f32x4 acc = (f32x4)0.f;
#pragma unroll
      for (int c = 0; c < 2; ++c) {
        const bf16x8 kb = *(const bf16x8*)(kf + (t * 2 + c) * 512 + lane * 8);
        acc = __builtin_amdgcn_mfma_f32_16x16x32_bf16(qa[c], kb, acc, 0, 0, 0);
      }
      sf[t] = acc;
    }

    // ---- mask + online softmax (rows = quad*4+r, cols = 16t+n) ----
    const bool diag = (k0 == q0);
#pragma unroll
    for (int t = 0; t < 4; ++t) {
      const float am_t = am_s[t * 16 + n];
      const int key_g = k0 + t * 16 + n;
#pragma unroll
      for (int r = 0; r < 4; ++r) {
        float s = sf[t][r] + am_t;
        if (diag) {
          const int qrow = q0 + w * 16 + quad * 4 + r;
          if (key_g > qrow) s = -10000.0f + am_t;
        }
        sf[t][r] = s;
      }
    }
#pragma unroll
    for (int r = 0; r < 4; ++r) {
      float mx = fmaxf(fmaxf(sf[0][r], sf[1][r]), fmaxf(sf[2][r], sf[3][r]));
#pragma unroll
      for (int msk = 1; msk <= 8; msk <<= 1) mx = fmaxf(mx, __shfl_xor(mx, msk));
      const float mn = fmaxf(m_r[r], mx);
      const float al = __expf(m_r[r] - mn);
      float sum = 0.f;
#pragma unroll
      for (int t = 0; t < 4; ++t) {
        const float p = __expf(sf[t][r] - mn);
        ptl[w][quad * 4 + r][t * 16 + n] = p;
        sum += p;
      }
#pragma unroll
      for (int msk = 1; msk <= 8; msk <<= 1) sum += __shfl_xor(sum, msk);
      l_r[r] = l_r[r] * al + sum;
      m_r[r] = mn;
#pragma unroll
      for (int u = 0; u < 4; ++u) O[u][r] *= al;
    }

    // ---- P: C-layout -> A-layout (wave-private LDS, same-wave ordering) ----
    bf16x8 pa[2];
#pragma unroll
    for (int c = 0; c < 2; ++c) {
      const float* prow = &ptl[w][n][c * 32 + quad * 8];
      const float4 a = *(const float4*)prow;
      const float4 b = *(const float4*)(prow + 4);
      pa[c][0] = f2bf(a.x); pa[c][1] = f2bf(a.y);
      pa[c][2] = f2bf(a.z); pa[c][3] = f2bf(a.w);
      pa[c][4] = f2bf(b.x); pa[c][5] = f2bf(b.y);
      pa[c][6] = f2bf(b.z); pa[c][7] = f2bf(b.w);
    }

    // ---- O += P*V ----
#pragma unroll
    for (int u = 0; u < 4; ++u) {
#pragma unroll
      for (int c = 0; c < 2; ++c) {
        const bf16x8 vb = *(const bf16x8*)(vf + (u * 2 + c) * 512 + lane * 8);
        O[u] = __builtin_amdgcn_mfma_f32_16x16x32_bf16(pa[c], vb, O[u], 0, 0, 0);
      }
    }
    __syncthreads();
  }

  // ---- epilogue: ctx[tok][hh*64 + dim] = O / l ----
#pragma unroll
  for (int r = 0; r < 4; ++r) {
    const float inv = 1.0f / l_r[r];
    const size_t tok = (size_t)bb * kT + q0 + w * 16 + quad * 4 + r;
#pragma unroll
    for (int u = 0; u < 4; ++u)
      ctx[tok * 1024 + hh * 64 + u * 16 + n] = O[u][r] * inv;
  }
}

// --------------------------------- launcher -------------------------------------
extern "C" void kernel_launch(void* const* d_in, const int* in_sizes, int n_in,
                              void* d_out, int out_size, void* d_ws, size_t ws_size,
                              hipStream_t stream) {
  const float* emb   = (const float*)d_in[0];
  const float* amask = (const float*)d_in[1];
  const float* ln1w  = (const float*)d_in[2];
  const float* ln1b  = (const float*)d_in[3];
  const float* attnw = (const float*)d_in[4];
  const float* attnb = (const float*)d_in[5];
  const float* projw = (const float*)d_in[6];
  const float* projb = (const float*)d_in[7];
  const float* ln2w  = (const float*)d_in[8];
  const float* ln2b  = (const float*)d_in[9];
  const float* fcw   = (const float*)d_in[10];
  const float* fcb   = (const float*)d_in[11];
  const float* fcpw  = (const float*)d_in[12];
  const float* fcpb  = (const float*)d_in[13];
  const float* lnfw  = (const float*)d_in[14];
  const float* lnfb  = (const float*)d_in[15];
  float* out = (float*)d_out;

  float* h   = (float*)d_ws;
  float* x   = h + (size_t)kM * kD;
  float* ctx = x + (size_t)kM * kD;
  float* big = ctx + (size_t)kM * kD;

  hipMemcpyAsync(h, emb, sizeof(float) * (size_t)kM * kD,
                 hipMemcpyDeviceToDevice, stream);

  const dim3 blk(256);
  for (int l = 0; l < kL; ++l) {
    ln_kernel<<<kM, blk, 0, stream>>>(h, ln1w + l * kD, ln1b + l * kD, x);
    gemm_kernel<false, false><<<dim3(3072 / 64, kM / 64), blk, 0, stream>>>(
        x, attnw + (size_t)l * kD * 3072, attnb + l * 3072, nullptr, big, 3072, kD);
    attn_kernel<<<dim3(kT / 64, kB * kH), blk, 0, stream>>>(big, amask, ctx);
    gemm_kernel<false, true><<<dim3(1024 / 64, kM / 64), blk, 0, stream>>>(
        ctx, projw + (size_t)l * kD * kD, projb + l * kD, h, h, 1024, kD);
    ln_kernel<<<kM, blk, 0, stream>>>(h, ln2w + l * kD, ln2b + l * kD, x);
    gemm_kernel<true, false><<<dim3(4096 / 64, kM / 64), blk, 0, stream>>>(
        x, fcw + (size_t)l * kD * kInner, fcb + l * kInner, nullptr, big, kInner, kD);
    gemm_kernel<false, true><<<dim3(1024 / 64, kM / 64), blk, 0, stream>>>(
        big, fcpw + (size_t)l * kInner * kD, fcpb + l * kD, h, h, 1024, kInner);
  }
  ln_kernel<<<kM, blk, 0, stream>>>(h, lnfw, lnfb, out);
}

// Round 3
// 3468.258 us; speedup vs baseline: 7.2079x; 3.7589x over previous
//
#include <hip/hip_runtime.h>
#include <math.h>

namespace {
constexpr int kB = 2;
constexpr int kT = 2048;
constexpr int kD = 1024;
constexpr int kH = 16;
constexpr int kL = 8;
constexpr int kInner = 4096;
constexpr int kM = kB * kT;  // 4096 token rows
constexpr float kEps = 1e-5f;
}

typedef __attribute__((ext_vector_type(8))) short bf16x8;
typedef __attribute__((ext_vector_type(4))) float f32x4;

typedef const __attribute__((address_space(1))) void* gas_t;
typedef __attribute__((address_space(3))) void* las_t;

__device__ __forceinline__ short f2bf(float f) {
  union { float f; unsigned u; } v{f};
  unsigned r = (v.u + 0x7FFF + ((v.u >> 16) & 1)) >> 16;
  return (short)r;
}

// ---------------- LayerNorm: one 256-thread block per row of 1024 ----------------
// OT = float (fp32 out) or short (bf16 out, feeds MFMA GEMM A)
template <typename OT>
__global__ __launch_bounds__(256) void ln_kernel(
    const float* __restrict__ in, const float* __restrict__ w,
    const float* __restrict__ b, OT* __restrict__ out) {
  const int row = blockIdx.x;
  const int tid = threadIdx.x;
  const float4 v = ((const float4*)(in + (size_t)row * kD))[tid];
  float sum = v.x + v.y + v.z + v.w;
  float sq = v.x * v.x + v.y * v.y + v.z * v.z + v.w * v.w;
#pragma unroll
  for (int off = 32; off > 0; off >>= 1) {
    sum += __shfl_down(sum, off);
    sq += __shfl_down(sq, off);
  }
  __shared__ float s1[4], s2[4];
  const int wave = tid >> 6, lane = tid & 63;
  if (lane == 0) { s1[wave] = sum; s2[wave] = sq; }
  __syncthreads();
  const float ts = s1[0] + s1[1] + s1[2] + s1[3];
  const float tq = s2[0] + s2[1] + s2[2] + s2[3];
  const float mean = ts * (1.0f / kD);
  const float var = tq * (1.0f / kD) - mean * mean;
  const float rs = rsqrtf(var + kEps);
  const float4 w4 = ((const float4*)w)[tid];
  const float4 b4 = ((const float4*)b)[tid];
  float4 o;
  o.x = (v.x - mean) * rs * w4.x + b4.x;
  o.y = (v.y - mean) * rs * w4.y + b4.y;
  o.z = (v.z - mean) * rs * w4.z + b4.z;
  o.w = (v.w - mean) * rs * w4.w + b4.w;
  if constexpr (sizeof(OT) == 4) {
    ((float4*)(out + (size_t)row * kD))[tid] = o;
  } else {
    short4 s4;
    s4.x = f2bf(o.x); s4.y = f2bf(o.y); s4.z = f2bf(o.z); s4.w = f2bf(o.w);
    ((short4*)(out + (size_t)row * kD))[tid] = s4;
  }
}

// ------------- per-layer weight convert+transpose: fp32 [K,N] -> bf16 [N,K] -----
// Grid 3072 blocks: attnw 768 | projw 256 | fcw 1024 | fcpw 1024 (64x64 tiles)
__global__ __launch_bounds__(256) void convT_kernel(
    const float* __restrict__ aw, const float* __restrict__ pw,
    const float* __restrict__ fw, const float* __restrict__ gw,
    short* __restrict__ awT, short* __restrict__ pwT,
    short* __restrict__ fwT, short* __restrict__ gwT) {
  __shared__ short t[64][66];
  int b = blockIdx.x;
  const float* src; short* dst; int K, N, tk, tn;
  if (b < 768)       { src = aw; dst = awT; K = 1024; N = 3072; tk = b / 48; tn = b % 48; }
  else if (b < 1024) { b -= 768;  src = pw; dst = pwT; K = 1024; N = 1024; tk = b / 16; tn = b % 16; }
  else if (b < 2048) { b -= 1024; src = fw; dst = fwT; K = 1024; N = 4096; tk = b / 64; tn = b % 64; }
  else               { b -= 2048; src = gw; dst = gwT; K = 4096; N = 1024; tk = b / 16; tn = b % 16; }
  const int k0 = tk * 64, n0 = tn * 64;
  const int tr = threadIdx.x >> 4, tc4 = (threadIdx.x & 15) << 2;
#pragma unroll
  for (int i = 0; i < 4; ++i) {
    const int k = tr + i * 16;
    const float4 v = *(const float4*)(src + (size_t)(k0 + k) * N + n0 + tc4);
    t[k][tc4 + 0] = f2bf(v.x); t[k][tc4 + 1] = f2bf(v.y);
    t[k][tc4 + 2] = f2bf(v.z); t[k][tc4 + 3] = f2bf(v.w);
  }
  __syncthreads();
#pragma unroll
  for (int i = 0; i < 4; ++i) {
    const int n = tr + i * 16;
    short4 o;
    o.x = t[tc4 + 0][n]; o.y = t[tc4 + 1][n];
    o.z = t[tc4 + 2][n]; o.w = t[tc4 + 3][n];
    *(short4*)(dst + (size_t)(n0 + n) * K + k0 + tc4) = o;
  }
}

// ---------------- bf16 MFMA GEMM: C[M,N] = A[M,K]·B^T[N,K]^T + bias -------------
// 128x128 tile, BK=64, 256 threads = 4 waves, each wave 4x4 of 16x16x32 MFMA.
// global_load_lds width-16 staging; XOR chunk swizzle (chunk ^ (row&7)) applied
// on the GLOBAL source so staging stays coalesced and ds_read_b128 frag reads
// land 2-way-per-bank (free, m136). OUT: 0 = bf16 store (+opt RELU),
// 1 = fp32 store with fp32 residual add.
template <int OUT, bool RELU>
__global__ __launch_bounds__(256) void mfma_gemm(
    const short* __restrict__ A, const short* __restrict__ BT,
    const float* __restrict__ bias, const float* __restrict__ res,
    void* __restrict__ Cout, int N, int K) {
  __shared__ __align__(16) short As[128 * 64];
  __shared__ __align__(16) short Bs[128 * 64];
  const int tid = threadIdx.x;
  const int w = tid >> 6, lane = tid & 63;
  const int n16 = lane & 15, quad = lane >> 4;
  const int m0 = blockIdx.y * 128, n0 = blockIdx.x * 128;
  const int wr = (w >> 1) * 64, wc = (w & 1) * 64;

  f32x4 acc[4][4];
#pragma unroll
  for (int i = 0; i < 4; ++i)
#pragma unroll
    for (int j = 0; j < 4; ++j) acc[i][j] = (f32x4)0.f;

  const int srow = lane >> 3;    // row within 8-row staging group
  const int schunk = lane & 7;   // 16B chunk this lane fills in LDS

  for (int k0 = 0; k0 < K; k0 += 64) {
#pragma unroll
    for (int s = 0; s < 4; ++s) {
      const int r = (w * 4 + s) * 8 + srow;       // tile row 0..127
      const int cs = schunk ^ (r & 7);            // swizzled source chunk
      __builtin_amdgcn_global_load_lds(
          (gas_t)(const void*)(A + (size_t)(m0 + r) * K + k0 + cs * 8),
          (las_t)(void*)(As + (w * 4 + s) * 8 * 64), 16, 0, 0);
      __builtin_amdgcn_global_load_lds(
          (gas_t)(const void*)(BT + (size_t)(n0 + r) * K + k0 + cs * 8),
          (las_t)(void*)(Bs + (w * 4 + s) * 8 * 64), 16, 0, 0);
    }
    __syncthreads();
#pragma unroll
    for (int kc = 0; kc < 2; ++kc) {
      bf16x8 af[4], bfr[4];
#pragma unroll
      for (int i = 0; i < 4; ++i) {
        const int m = wr + i * 16 + n16;
        af[i] = *(const bf16x8*)(As + m * 64 + (((kc << 2) + quad) ^ (m & 7)) * 8);
        const int n = wc + i * 16 + n16;
        bfr[i] = *(const bf16x8*)(Bs + n * 64 + (((kc << 2) + quad) ^ (n & 7)) * 8);
      }
#pragma unroll
      for (int i = 0; i < 4; ++i)
#pragma unroll
        for (int j = 0; j < 4; ++j)
          acc[i][j] = __builtin_amdgcn_mfma_f32_16x16x32_bf16(af[i], bfr[j],
                                                              acc[i][j], 0, 0, 0);
    }
    __syncthreads();
  }

#pragma unroll
  for (int j = 0; j < 4; ++j) {
    const int n = n0 + wc + j * 16 + n16;
    const float bv = bias[n];
#pragma unroll
    for (int i = 0; i < 4; ++i) {
#pragma unroll
      for (int r = 0; r < 4; ++r) {
        const int m = m0 + wr + i * 16 + quad * 4 + r;
        float v = acc[i][j][r] + bv;
        if (OUT == 1) {
          ((float*)Cout)[(size_t)m * N + n] = v + res[(size_t)m * N + n];
        } else {
          if (RELU) v = fmaxf(v, 0.f);
          ((short*)Cout)[(size_t)m * N + n] = f2bf(v);
        }
      }
    }
  }
}

// ---------------- MFMA bf16 flash attention (bf16 qkv in, bf16 ctx out) ---------
// Block: one (b,h), 64 q rows. 4 waves x 16-q-row tile. K-tile = 64 keys.
// K staged via global_load_lds directly into fragment order; V manual transpose
// scatter. Softmax scale 0.125 applied post-MFMA (matches ref order exactly).
__global__ __launch_bounds__(256) void attn_kernel(
    const short* __restrict__ qkv, const float* __restrict__ amaskp,
    short* __restrict__ ctx) {
  __shared__ __align__(16) short kf[8 * 512];   // 8 KB
  __shared__ __align__(16) short vf[8 * 512];   // 8 KB
  __shared__ float ptl[4][16][65];              // wave-private P slabs
  __shared__ float am_s[64];

  const int tid = threadIdx.x;
  const int w = tid >> 6;
  const int lane = tid & 63;
  const int n16 = lane & 15;
  const int quad = lane >> 4;
  const int bh = blockIdx.y;
  const int bb = bh >> 4;
  const int hh = bh & 15;
  const int qb = gridDim.x - 1 - blockIdx.x;  // heavy causal blocks first
  const int q0 = qb * 64;

  const short* base = qkv + (size_t)bb * kT * 3072;
  const short* kbase = base + 1024 + hh * 64;
  const short* vbase = base + 2048 + hh * 64;

  // Q A-fragments: direct bf16 loads, zero conversion
  bf16x8 qa[2];
  {
    const short* qp = base + (size_t)(q0 + w * 16 + n16) * 3072 + hh * 64 + quad * 8;
    qa[0] = *(const bf16x8*)qp;
    qa[1] = *(const bf16x8*)(qp + 32);
  }

  f32x4 O[4];
#pragma unroll
  for (int u = 0; u < 4; ++u) O[u] = (f32x4)0.f;
  float m_r[4], l_r[4];
#pragma unroll
  for (int r = 0; r < 4; ++r) { m_r[r] = -1e30f; l_r[r] = 0.f; }

  for (int k0 = 0; k0 <= q0; k0 += 64) {
    // K: frag (t=w, c): lane L <- K[k0+16t+(L&15)][32c+8*(L>>4)..+8]
#pragma unroll
    for (int c = 0; c < 2; ++c) {
      __builtin_amdgcn_global_load_lds(
          (gas_t)(const void*)(kbase + (size_t)(k0 + w * 16 + n16) * 3072 +
                               c * 32 + quad * 8),
          (las_t)(void*)(kf + (w * 2 + c) * 512), 16, 0, 0);
    }
    // V: manual transpose scatter into B-frag order
#pragma unroll
    for (int i = 0; i < 2; ++i) {
      const int id = tid * 2 + i;              // 0..511 chunk id
      const int key = id >> 3, c8 = id & 7;    // key, 8-dim chunk
      const bf16x8 vv = *(const bf16x8*)(vbase + (size_t)(k0 + key) * 3072 + c8 * 8);
      const int u = c8 >> 1;
      const int cc = key >> 5;
      const int lbase = ((key & 31) >> 3) * 16 + (c8 & 1) * 8;
      short* dst = vf + (u * 2 + cc) * 512 + (key & 7);
#pragma unroll
      for (int j = 0; j < 8; ++j) dst[(lbase + j) * 8] = vv[j];
    }
    if (tid < 64)
      am_s[tid] = (1.0f - amaskp[bb * kT + k0 + tid]) * (-10000.0f);
    __syncthreads();

    // S = Q*K^T
    f32x4 sf[4];
#pragma unroll
    for (int t = 0; t < 4; ++t) {
      f32x4 a = (f32x4)0.f;
#pragma unroll
      for (int c = 0; c < 2; ++c) {
        const bf16x8 kb = *(const bf16x8*)(kf + (t * 2 + c) * 512 + lane * 8);
        a = __builtin_amdgcn_mfma_f32_16x16x32_bf16(qa[c], kb, a, 0, 0, 0);
      }
      sf[t] = a;
    }

    // scale + mask + online softmax (rows = quad*4+r, cols = 16t+n16)
    const bool diag = (k0 == q0);
#pragma unroll
    for (int t = 0; t < 4; ++t) {
      const float am_t = am_s[t * 16 + n16];
      const int key_g = k0 + t * 16 + n16;
#pragma unroll
      for (int r = 0; r < 4; ++r) {
        float s = sf[t][r] * 0.125f;
        if (diag && key_g > q0 + w * 16 + quad * 4 + r) s = -10000.0f;
        sf[t][r] = s + am_t;
      }
    }
#pragma unroll
    for (int r = 0; r < 4; ++r) {
      float mx = fmaxf(fmaxf(sf[0][r], sf[1][r]), fmaxf(sf[2][r], sf[3][r]));
#pragma unroll
      for (int msk = 1; msk <= 8; msk <<= 1) mx = fmaxf(mx, __shfl_xor(mx, msk));
      const float mn = fmaxf(m_r[r], mx);
      const float al = __expf(m_r[r] - mn);
      float sum = 0.f;
#pragma unroll
      for (int t = 0; t < 4; ++t) {
        const float p = __expf(sf[t][r] - mn);
        ptl[w][quad * 4 + r][t * 16 + n16] = p;
        sum += p;
      }
#pragma unroll
      for (int msk = 1; msk <= 8; msk <<= 1) sum += __shfl_xor(sum, msk);
      l_r[r] = l_r[r] * al + sum;
      m_r[r] = mn;
#pragma unroll
      for (int u = 0; u < 4; ++u) O[u][r] *= al;
    }

    // P: C-layout -> A-layout (wave-private LDS round trip)
    bf16x8 pa[2];
#pragma unroll
    for (int c = 0; c < 2; ++c) {
      const float* prow = &ptl[w][n16][c * 32 + quad * 8];
      const float4 a = *(const float4*)prow;
      const float4 b = *(const float4*)(prow + 4);
      pa[c][0] = f2bf(a.x); pa[c][1] = f2bf(a.y);
      pa[c][2] = f2bf(a.z); pa[c][3] = f2bf(a.w);
      pa[c][4] = f2bf(b.x); pa[c][5] = f2bf(b.y);
      pa[c][6] = f2bf(b.z); pa[c][7] = f2bf(b.w);
    }

    // O += P*V
#pragma unroll
    for (int u = 0; u < 4; ++u) {
#pragma unroll
      for (int c = 0; c < 2; ++c) {
        const bf16x8 vb = *(const bf16x8*)(vf + (u * 2 + c) * 512 + lane * 8);
        O[u] = __builtin_amdgcn_mfma_f32_16x16x32_bf16(pa[c], vb, O[u], 0, 0, 0);
      }
    }
    __syncthreads();
  }

  // epilogue: ctx bf16
#pragma unroll
  for (int r = 0; r < 4; ++r) {
    const float inv = 1.0f / l_r[r];
    const size_t tok = (size_t)bb * kT + q0 + w * 16 + quad * 4 + r;
#pragma unroll
    for (int u = 0; u < 4; ++u)
      ctx[tok * 1024 + hh * 64 + u * 16 + n16] = f2bf(O[u][r] * inv);
  }
}

// --------------------------------- launcher -------------------------------------
extern "C" void kernel_launch(void* const* d_in, const int* in_sizes, int n_in,
                              void* d_out, int out_size, void* d_ws, size_t ws_size,
                              hipStream_t stream) {
  const float* emb   = (const float*)d_in[0];
  const float* amask = (const float*)d_in[1];
  const float* ln1w  = (const float*)d_in[2];
  const float* ln1b  = (const float*)d_in[3];
  const float* attnw = (const float*)d_in[4];
  const float* attnb = (const float*)d_in[5];
  const float* projw = (const float*)d_in[6];
  const float* projb = (const float*)d_in[7];
  const float* ln2w  = (const float*)d_in[8];
  const float* ln2b  = (const float*)d_in[9];
  const float* fcw   = (const float*)d_in[10];
  const float* fcb   = (const float*)d_in[11];
  const float* fcpw  = (const float*)d_in[12];
  const float* fcpb  = (const float*)d_in[13];
  const float* lnfw  = (const float*)d_in[14];
  const float* lnfb  = (const float*)d_in[15];
  float* out = (float*)d_out;

  // ws layout (~92 MB): h fp32 | x bf16 | ctx bf16 | big bf16 | wT slab bf16
  float* h    = (float*)d_ws;                          // 4096x1024 fp32
  short* xb   = (short*)(h + (size_t)kM * kD);         // 4096x1024 bf16
  short* ctxb = xb + (size_t)kM * kD;                  // 4096x1024 bf16
  short* bigb = ctxb + (size_t)kM * kD;                // 4096x4096 bf16 (qkv/ffn)
  short* awT  = bigb + (size_t)kM * kInner;            // 3072x1024
  short* pwT  = awT + (size_t)3072 * 1024;             // 1024x1024
  short* fwT  = pwT + (size_t)1024 * 1024;             // 4096x1024
  short* gwT  = fwT + (size_t)4096 * 1024;             // 1024x4096

  hipMemcpyAsync(h, emb, sizeof(float) * (size_t)kM * kD,
                 hipMemcpyDeviceToDevice, stream);

  const dim3 blk(256);
  for (int l = 0; l < kL; ++l) {
    convT_kernel<<<3072, blk, 0, stream>>>(
        attnw + (size_t)l * kD * 3072, projw + (size_t)l * kD * kD,
        fcw + (size_t)l * kD * kInner, fcpw + (size_t)l * kInner * kD,
        awT, pwT, fwT, gwT);
    ln_kernel<short><<<kM, blk, 0, stream>>>(h, ln1w + l * kD, ln1b + l * kD, xb);
    mfma_gemm<0, false><<<dim3(3072 / 128, kM / 128), blk, 0, stream>>>(
        xb, awT, attnb + l * 3072, nullptr, bigb, 3072, 1024);
    attn_kernel<<<dim3(kT / 64, kB * kH), blk, 0, stream>>>(bigb, amask, ctxb);
    mfma_gemm<1, false><<<dim3(1024 / 128, kM / 128), blk, 0, stream>>>(
        ctxb, pwT, projb + l * kD, h, h, 1024, 1024);
    ln_kernel<short><<<kM, blk, 0, stream>>>(h, ln2w + l * kD, ln2b + l * kD, xb);
    mfma_gemm<0, true><<<dim3(4096 / 128, kM / 128), blk, 0, stream>>>(
        xb, fwT, fcb + l * kInner, nullptr, bigb, 4096, 1024);
    mfma_gemm<1, false><<<dim3(1024 / 128, kM / 128), blk, 0, stream>>>(
        bigb, gwT, fcpb + l * kD, h, h, 1024, 4096);
  }
  ln_kernel<float><<<kM, blk, 0, stream>>>(h, lnfw, lnfb, out);
}